// Round 9
// baseline (168.821 us; speedup 1.0000x reference)
//
#include <hip/hip_runtime.h>

typedef _Float16 half8 __attribute__((ext_vector_type(8)));
typedef _Float16 half4 __attribute__((ext_vector_type(4)));
typedef float f32x4 __attribute__((ext_vector_type(4)));

// ---------------------------------------------------------------------------
// Sizes: B=8, C=512, H=8, D=64, N=1024. Projection: M=1536 (q|k|v), K=512.
// R9: ONE pre-attn kernel. A staged straight from raw f32 W (K-contiguous, no
// transpose, no select chains), B straight from raw x (in-register transpose,
// literal component indices), bias raw in epilogue, rel-prep as extra blocks.
// Pitch-40 LDS rows: staging writes and frag reads conflict-free (20 dw mod 32
// spreads 16-row column slices over all banks).
// ---------------------------------------------------------------------------

__global__ __launch_bounds__(256, 3) void k_proj_all(
    const float* __restrict__ Wq, const float* __restrict__ Wk,
    const float* __restrict__ Wv, const float* __restrict__ bq,
    const float* __restrict__ bk, const float* __restrict__ bv,
    const float* __restrict__ x, const float* __restrict__ rel_h,
    const float* __restrict__ rel_w, _Float16* __restrict__ q2,
    _Float16* __restrict__ k2, _Float16* __restrict__ vb,
    _Float16* __restrict__ rel2) {
    __shared__ __align__(16) _Float16 As[2 * 128 * 40];   // 20480 B
    __shared__ __align__(16) _Float16 Bs[2 * 128 * 40];   // 20480 B
    int bid = blockIdx.x;
    int t = threadIdx.x;

    if (bid >= 768) {            // ---- rel2 = (rel_h + rel_w) -> fp16 [h][n][d]
        int tid = (bid - 768) * 256 + t;    // 65536
        int h = tid >> 13;
        int rem = tid & 8191;
        int n = rem >> 3;
        int g = rem & 7;
        int hh = n & 31, ww = n >> 5;
        half8 o;
#pragma unroll
        for (int j = 0; j < 8; ++j) {
            int d = g * 8 + j;
            o[j] = (_Float16)(rel_h[(h * 64 + d) * 32 + hh] + rel_w[(h * 64 + d) * 32 + ww]);
        }
        *(half8*)(rel2 + ((size_t)h * 1024 + n) * 64 + g * 8) = o;
        return;
    }

    // ---- GEMM: block (b, mb, nb); b = bid&7 -> XCD-local x panel in L2 ----
    int lane = t & 63, w = t >> 6;
    int lm = lane & 15, lq = lane >> 4;
    int wr = (w >> 1) * 64, wc = (w & 1) * 64;
    int b = bid & 7;
    int rest = bid >> 3;                     // 0..95
    int mb = (rest % 12) * 128, nb = (rest / 12) * 128;
    int msel = mb >> 9;                      // 0=q 1=k 2=v
    int mrow0 = mb & 511;
    const float* Wsel = (msel == 0) ? Wq : ((msel == 1) ? Wk : Wv);

    // A staging map: thread -> (row am, K-half akh); 32 contiguous c per thread
    int am = t >> 1;                         // 0..127
    int akh = t & 1;
    const float* wrow = Wsel + (size_t)(mrow0 + am) * 512 + akh * 32;
    // B staging map: thread -> (row-quad nq, c-octet ch)
    int nq = t & 31;
    int ch = t >> 5;                         // 0..7
    int bkh = ch >> 2;
    int c32 = (ch & 3) * 8;
    const float* xrow = x + (size_t)b * 512 * 1024 + nb + nq * 4;

    f32x4 acc[4][4];
#pragma unroll
    for (int i = 0; i < 4; ++i)
#pragma unroll
        for (int j = 0; j < 4; ++j) acc[i][j] = {0.f, 0.f, 0.f, 0.f};

    for (int k0 = 0; k0 < 512; k0 += 64) {
        // ---- A: raw W f32 -> fp16, K-contiguous (no transpose) ----
        {
            const float* wp = wrow + k0;
            float4 wf[8];
#pragma unroll
            for (int i = 0; i < 8; ++i) wf[i] = ((const float4*)wp)[i];
            _Float16* arow = &As[akh * 5120 + am * 40];
#pragma unroll
            for (int q = 0; q < 2; ++q) {
                half8 h;
                h[0] = (_Float16)wf[q * 4 + 0].x; h[1] = (_Float16)wf[q * 4 + 0].y;
                h[2] = (_Float16)wf[q * 4 + 0].z; h[3] = (_Float16)wf[q * 4 + 0].w;
                h[4] = (_Float16)wf[q * 4 + 1].x; h[5] = (_Float16)wf[q * 4 + 1].y;
                h[6] = (_Float16)wf[q * 4 + 1].z; h[7] = (_Float16)wf[q * 4 + 1].w;
                half8 h2;
                h2[0] = (_Float16)wf[q * 4 + 2].x; h2[1] = (_Float16)wf[q * 4 + 2].y;
                h2[2] = (_Float16)wf[q * 4 + 2].z; h2[3] = (_Float16)wf[q * 4 + 2].w;
                h2[4] = (_Float16)wf[q * 4 + 3].x; h2[5] = (_Float16)wf[q * 4 + 3].y;
                h2[6] = (_Float16)wf[q * 4 + 3].z; h2[7] = (_Float16)wf[q * 4 + 3].w;
                *(half8*)(arow + q * 16) = h;
                *(half8*)(arow + q * 16 + 8) = h2;
            }
        }
        // ---- B: raw x f32 -> fp16, in-register transpose, literal indices ----
        {
            const float* xp = xrow + (size_t)(k0 + ch * 8) * 1024;
            float4 xf[8];
#pragma unroll
            for (int i = 0; i < 8; ++i) xf[i] = *(const float4*)(xp + (size_t)i * 1024);
            _Float16* bbase = &Bs[bkh * 5120 + c32];
#pragma unroll
            for (int j = 0; j < 4; ++j) {
                half8 h;
                h[0] = (_Float16)((const float*)&xf[0])[j];
                h[1] = (_Float16)((const float*)&xf[1])[j];
                h[2] = (_Float16)((const float*)&xf[2])[j];
                h[3] = (_Float16)((const float*)&xf[3])[j];
                h[4] = (_Float16)((const float*)&xf[4])[j];
                h[5] = (_Float16)((const float*)&xf[5])[j];
                h[6] = (_Float16)((const float*)&xf[6])[j];
                h[7] = (_Float16)((const float*)&xf[7])[j];
                *(half8*)(bbase + (nq * 4 + j) * 40) = h;
            }
        }
        __syncthreads();
#pragma unroll
        for (int kh = 0; kh < 2; ++kh) {
            half8 af[4], bfr[4];
#pragma unroll
            for (int mt = 0; mt < 4; ++mt)
                af[mt] = *(half8*)&As[kh * 5120 + (wr + mt * 16 + lm) * 40 + lq * 8];
#pragma unroll
            for (int nt = 0; nt < 4; ++nt)
                bfr[nt] = *(half8*)&Bs[kh * 5120 + (wc + nt * 16 + lm) * 40 + lq * 8];
#pragma unroll
            for (int mt = 0; mt < 4; ++mt)
#pragma unroll
                for (int nt = 0; nt < 4; ++nt)
                    acc[mt][nt] = __builtin_amdgcn_mfma_f32_16x16x32_f16(af[mt], bfr[nt], acc[mt][nt], 0, 0, 0);
        }
        __syncthreads();
    }
    // Epilogue: 0=q (x log2e for exp2 softmax), 1=k ([bh][n][d]), 2=v ([bh][d][n]).
    const float* bsel = (msel == 0) ? bq : ((msel == 1) ? bk : bv);
    int hloc = (mrow0 + wr) >> 6;
    size_t bh = (size_t)b * 8 + hloc;
    if (msel < 2) {
        float sc = (msel == 0) ? 1.44269504089f : 1.0f;
        _Float16* dst = (msel == 0 ? q2 : k2) + bh * 1024 * 64;
#pragma unroll
        for (int mt = 0; mt < 4; ++mt) {
            int d0 = mt * 16 + lq * 4;
            float bi0 = bsel[mrow0 + wr + d0];
            float bi1 = bsel[mrow0 + wr + d0 + 1];
            float bi2 = bsel[mrow0 + wr + d0 + 2];
            float bi3 = bsel[mrow0 + wr + d0 + 3];
#pragma unroll
            for (int nt = 0; nt < 4; ++nt) {
                int n = nb + wc + nt * 16 + lm;
                half4 o;
                o[0] = (_Float16)((acc[mt][nt][0] + bi0) * sc);
                o[1] = (_Float16)((acc[mt][nt][1] + bi1) * sc);
                o[2] = (_Float16)((acc[mt][nt][2] + bi2) * sc);
                o[3] = (_Float16)((acc[mt][nt][3] + bi3) * sc);
                *(half4*)(dst + (size_t)n * 64 + d0) = o;
            }
        }
    } else {
        _Float16* dst = vb + bh * 64 * 1024;
#pragma unroll
        for (int mt = 0; mt < 4; ++mt)
#pragma unroll
            for (int reg = 0; reg < 4; ++reg) {
                int d = mt * 16 + lq * 4 + reg;
                float bi = bsel[mrow0 + wr + d];
#pragma unroll
                for (int nt = 0; nt < 4; ++nt) {
                    int n = nb + wc + nt * 16 + lm;
                    dst[(size_t)d * 1024 + n] = (_Float16)(acc[mt][nt][reg] + bi);
                }
            }
    }
}

// Flash attention, fp16, S^T orientation, Mtile=128 (2 q-tiles per block share
// K/V staging, barriers, and kf fragments). Named-scalar prefetch. exp2
// softmax (q pre-scaled). XCD-locality: lin&63 = (b,h). R0-baseline verbatim
// (best measured 55.5 us; R2/R3/R4/R6 perturbations all neutral-or-worse).
__global__ __launch_bounds__(256, 3) void k_attn(const _Float16* __restrict__ q2,
                                                 const _Float16* __restrict__ k2,
                                                 const _Float16* __restrict__ rel2,
                                                 const _Float16* __restrict__ vb,
                                                 float* __restrict__ out) {
    __shared__ __align__(16) char pool[45056];
    _Float16* kb_s = (_Float16*)pool;            // [64][136] = 17408 B (B-rows [k|q]; phase-0: A-rows)
    _Float16* v_s  = (_Float16*)(pool + 17408);  // [64][72]  =  9216 B
    _Float16* p_s  = (_Float16*)(pool + 26624);  // [128 m][72 n] = 18432 B (wave-private rows)
    int t = threadIdx.x;
    int lane = t & 63, w = t >> 6;
    int lm = lane & 15, lq = lane >> 4;
    int lin = blockIdx.x;
    int mt0 = lin >> 6;          // 0..7 (128 q-rows each)
    int bh_ = lin & 63;
    int h = bh_ & 7, b = bh_ >> 3;
    size_t bh = (size_t)b * 8 + h;
    const _Float16* q2b = q2 + bh * 1024 * 64;
    const _Float16* k2b = k2 + bh * 1024 * 64;
    const _Float16* relb = rel2 + (size_t)h * 1024 * 64;
    const _Float16* vbb = vb + bh * 64 * 1024;
    float* outb = out + bh * 64 * 1024 + mt0 * 128;

    int r = t >> 2, part = t & 3;
    const _Float16* ksrc = ((part < 2) ? (k2b + part * 32) : (q2b + (part - 2) * 32));
    int vc = (t & 3) * 16;
    const _Float16* vsrcb = vbb + (size_t)r * 1024 + vc;
    _Float16* kdst = kb_s + r * 136 + part * 32;
    _Float16* vdst = v_s + r * 72 + vc;

    // prefetch tile 0 into named scalar registers
    uint4 kc0, kc1, kc2, kc3, vv0, vv1;
    {
        const uint4* s_ = (const uint4*)(ksrc + (size_t)r * 64);
        kc0 = s_[0]; kc1 = s_[1]; kc2 = s_[2]; kc3 = s_[3];
        const uint4* v_ = (const uint4*)vsrcb;
        vv0 = v_[0]; vv1 = v_[1];
    }

    // Phase 0 round A: stage A-rows [q | rel] for m = mt0*128 + 0..63
    {
        int n = mt0 * 128 + r;
        const _Float16* src = (part < 2) ? (q2b + (size_t)n * 64 + part * 32)
                                         : (relb + (size_t)n * 64 + (part - 2) * 32);
        ((uint4*)kdst)[0] = ((const uint4*)src)[0];
        ((uint4*)kdst)[1] = ((const uint4*)src)[1];
        ((uint4*)kdst)[2] = ((const uint4*)src)[2];
        ((uint4*)kdst)[3] = ((const uint4*)src)[3];
    }
    __syncthreads();
    half8 ah0[4], ah1[4];
#pragma unroll
    for (int kk = 0; kk < 4; ++kk)
        ah0[kk] = *(half8*)&kb_s[(w * 16 + lm) * 136 + kk * 32 + lq * 8];
    __syncthreads();
    // Phase 0 round B: rows m = mt0*128 + 64..127
    {
        int n = mt0 * 128 + 64 + r;
        const _Float16* src = (part < 2) ? (q2b + (size_t)n * 64 + part * 32)
                                         : (relb + (size_t)n * 64 + (part - 2) * 32);
        ((uint4*)kdst)[0] = ((const uint4*)src)[0];
        ((uint4*)kdst)[1] = ((const uint4*)src)[1];
        ((uint4*)kdst)[2] = ((const uint4*)src)[2];
        ((uint4*)kdst)[3] = ((const uint4*)src)[3];
    }
    __syncthreads();
#pragma unroll
    for (int kk = 0; kk < 4; ++kk)
        ah1[kk] = *(half8*)&kb_s[(w * 16 + lm) * 136 + kk * 32 + lq * 8];
    __syncthreads();   // ah1 reads complete before first K ds_write

    f32x4 acco0[4], acco1[4];
#pragma unroll
    for (int i = 0; i < 4; ++i) { acco0[i] = {0.f, 0.f, 0.f, 0.f}; acco1[i] = {0.f, 0.f, 0.f, 0.f}; }
    float mrun0 = -3e38f, lrun0 = 0.f, mrun1 = -3e38f, lrun1 = 0.f;

    for (int kt = 0; kt < 16; ++kt) {
        ((uint4*)kdst)[0] = kc0;
        ((uint4*)kdst)[1] = kc1;
        ((uint4*)kdst)[2] = kc2;
        ((uint4*)kdst)[3] = kc3;
        ((uint4*)vdst)[0] = vv0;
        ((uint4*)vdst)[1] = vv1;
        __syncthreads();
        int nn = ((kt + 1) & 15) * 64;
        const uint4* s_ = (const uint4*)(ksrc + (size_t)(nn + r) * 64);
        uint4 kn0 = s_[0], kn1 = s_[1], kn2 = s_[2], kn3 = s_[3];
        const uint4* v_ = (const uint4*)(vsrcb + nn);
        uint4 vn0 = v_[0], vn1 = v_[1];
        // S^T: s0/s1[ct][reg] -> n = ct*16 + lq*4 + reg, m = w*16 + lm (+64 for s1)
        f32x4 s0[4], s1[4];
#pragma unroll
        for (int ct = 0; ct < 4; ++ct) { s0[ct] = {0.f, 0.f, 0.f, 0.f}; s1[ct] = {0.f, 0.f, 0.f, 0.f}; }
#pragma unroll
        for (int ct = 0; ct < 4; ++ct) {
            half8 kf[4];
#pragma unroll
            for (int kk = 0; kk < 4; ++kk)
                kf[kk] = *(half8*)&kb_s[(ct * 16 + lm) * 136 + kk * 32 + lq * 8];
#pragma unroll
            for (int kk = 0; kk < 4; ++kk) {
                s0[ct] = __builtin_amdgcn_mfma_f32_16x16x32_f16(kf[kk], ah0[kk], s0[ct], 0, 0, 0);
                s1[ct] = __builtin_amdgcn_mfma_f32_16x16x32_f16(kf[kk], ah1[kk], s1[ct], 0, 0, 0);
            }
        }
        // softmax tile 0 (per-lane column m; exp2 domain)
        {
            float mx = -3e38f;
#pragma unroll
            for (int ct = 0; ct < 4; ++ct)
#pragma unroll
                for (int reg = 0; reg < 4; ++reg) mx = fmaxf(mx, s0[ct][reg]);
            mx = fmaxf(mx, __shfl_xor(mx, 16));
            mx = fmaxf(mx, __shfl_xor(mx, 32));
            float mnew = fmaxf(mrun0, mx);
            float al_ = exp2f(mrun0 - mnew);
            float rs = 0.f;
#pragma unroll
            for (int ct = 0; ct < 4; ++ct) {
                float p0 = exp2f(s0[ct][0] - mnew);
                float p1 = exp2f(s0[ct][1] - mnew);
                float p2 = exp2f(s0[ct][2] - mnew);
                float p3 = exp2f(s0[ct][3] - mnew);
                rs += (p0 + p1) + (p2 + p3);
                half4 o; o[0] = (_Float16)p0; o[1] = (_Float16)p1; o[2] = (_Float16)p2; o[3] = (_Float16)p3;
                *(half4*)&p_s[(w * 16 + lm) * 72 + ct * 16 + lq * 4] = o;
            }
            rs += __shfl_xor(rs, 16);
            rs += __shfl_xor(rs, 32);
            lrun0 = lrun0 * al_ + rs;
            mrun0 = mnew;
#pragma unroll
            for (int dt = 0; dt < 4; ++dt) {
                acco0[dt][0] *= al_; acco0[dt][1] *= al_;
                acco0[dt][2] *= al_; acco0[dt][3] *= al_;
            }
        }
        // softmax tile 1
        {
            float mx = -3e38f;
#pragma unroll
            for (int ct = 0; ct < 4; ++ct)
#pragma unroll
                for (int reg = 0; reg < 4; ++reg) mx = fmaxf(mx, s1[ct][reg]);
            mx = fmaxf(mx, __shfl_xor(mx, 16));
            mx = fmaxf(mx, __shfl_xor(mx, 32));
            float mnew = fmaxf(mrun1, mx);
            float al_ = exp2f(mrun1 - mnew);
            float rs = 0.f;
#pragma unroll
            for (int ct = 0; ct < 4; ++ct) {
                float p0 = exp2f(s1[ct][0] - mnew);
                float p1 = exp2f(s1[ct][1] - mnew);
                float p2 = exp2f(s1[ct][2] - mnew);
                float p3 = exp2f(s1[ct][3] - mnew);
                rs += (p0 + p1) + (p2 + p3);
                half4 o; o[0] = (_Float16)p0; o[1] = (_Float16)p1; o[2] = (_Float16)p2; o[3] = (_Float16)p3;
                *(half4*)&p_s[(64 + w * 16 + lm) * 72 + ct * 16 + lq * 4] = o;
            }
            rs += __shfl_xor(rs, 16);
            rs += __shfl_xor(rs, 32);
            lrun1 = lrun1 * al_ + rs;
            mrun1 = mnew;
#pragma unroll
            for (int dt = 0; dt < 4; ++dt) {
                acco1[dt][0] *= al_; acco1[dt][1] *= al_;
                acco1[dt][2] *= al_; acco1[dt][3] *= al_;
            }
        }
        // PV for both tiles; v fragments shared
        half8 p0f[2], p1f[2];
#pragma unroll
        for (int ch = 0; ch < 2; ++ch) {
            p0f[ch] = *(half8*)&p_s[(w * 16 + lm) * 72 + ch * 32 + lq * 8];
            p1f[ch] = *(half8*)&p_s[(64 + w * 16 + lm) * 72 + ch * 32 + lq * 8];
        }
#pragma unroll
        for (int dt = 0; dt < 4; ++dt) {
            half8 vf0 = *(half8*)&v_s[(dt * 16 + lm) * 72 + lq * 8];
            half8 vf1 = *(half8*)&v_s[(dt * 16 + lm) * 72 + 32 + lq * 8];
            acco0[dt] = __builtin_amdgcn_mfma_f32_16x16x32_f16(vf0, p0f[0], acco0[dt], 0, 0, 0);
            acco0[dt] = __builtin_amdgcn_mfma_f32_16x16x32_f16(vf1, p0f[1], acco0[dt], 0, 0, 0);
            acco1[dt] = __builtin_amdgcn_mfma_f32_16x16x32_f16(vf0, p1f[0], acco1[dt], 0, 0, 0);
            acco1[dt] = __builtin_amdgcn_mfma_f32_16x16x32_f16(vf1, p1f[1], acco1[dt], 0, 0, 0);
        }
        __syncthreads();   // all reads of kb_s/v_s done before next ds_write
        kc0 = kn0; kc1 = kn1; kc2 = kn2; kc3 = kn3;
        vv0 = vn0; vv1 = vn1;
    }
    float li0 = 1.f / lrun0, li1 = 1.f / lrun1;
#pragma unroll
    for (int dt = 0; dt < 4; ++dt)
#pragma unroll
        for (int reg = 0; reg < 4; ++reg) {
            int d = dt * 16 + lq * 4 + reg;
            outb[(size_t)d * 1024 + w * 16 + lm] = acco0[dt][reg] * li0;
            outb[(size_t)d * 1024 + 64 + w * 16 + lm] = acco1[dt][reg] * li1;
        }
}

extern "C" void kernel_launch(void* const* d_in, const int* in_sizes, int n_in,
                              void* d_out, int out_size, void* d_ws, size_t ws_size,
                              hipStream_t stream) {
    const float* x     = (const float*)d_in[0];
    const float* Wq    = (const float*)d_in[1];
    const float* bq    = (const float*)d_in[2];
    const float* Wk    = (const float*)d_in[3];
    const float* bk    = (const float*)d_in[4];
    const float* Wv    = (const float*)d_in[5];
    const float* bv    = (const float*)d_in[6];
    const float* rel_h = (const float*)d_in[7];
    const float* rel_w = (const float*)d_in[8];
    char* ws = (char*)d_ws;
    _Float16* q2   = (_Float16*)(ws);               //  8,388,608 B
    _Float16* k2   = (_Float16*)(ws + 8388608);     //  8,388,608 B -> 16,777,216
    _Float16* vb   = (_Float16*)(ws + 16777216);    //  8,388,608 B -> 25,165,824
    _Float16* rel2 = (_Float16*)(ws + 25165824);    //  1,048,576 B -> 26,214,400
    float* out = (float*)d_out;

    hipLaunchKernelGGL(k_proj_all, dim3(1024), dim3(256), 0, stream,
                       Wq, Wk, Wv, bq, bk, bv, x, rel_h, rel_w, q2, k2, vb, rel2);
    hipLaunchKernelGGL(k_attn,     dim3(512),  dim3(256), 0, stream, q2, k2, rel2, vb, out);
}

// Round 10
// 156.742 us; speedup vs baseline: 1.0771x; 1.0771x over previous
//
#include <hip/hip_runtime.h>

typedef _Float16 half8 __attribute__((ext_vector_type(8)));
typedef _Float16 half4 __attribute__((ext_vector_type(4)));
typedef __fp16 fp16x2 __attribute__((ext_vector_type(2)));
typedef float f32x4 __attribute__((ext_vector_type(4)));

__device__ __forceinline__ void glds16(const void* g, void* l) {
    __builtin_amdgcn_global_load_lds(
        (const __attribute__((address_space(1))) unsigned int*)g,
        (__attribute__((address_space(3))) unsigned int*)l, 16, 0, 0);
}

// gfx950 VALU cross-lane swaps (both operands modified).
__device__ __forceinline__ void swap32(unsigned int& a, unsigned int& b) {
    asm volatile("v_permlane32_swap_b32 %0, %1" : "+v"(a), "+v"(b));
}
__device__ __forceinline__ void swap16(unsigned int& a, unsigned int& b) {
    asm volatile("v_permlane16_swap_b32 %0, %1" : "+v"(a), "+v"(b));
}

// ---------------------------------------------------------------------------
// Sizes: B=8, C=512, H=8, D=64, N=1024. Projection: M=1536 (q|k|v), K=512 fp16.
// ---------------------------------------------------------------------------

// Merged prep: [0,384) pack W->fp16; [384,1408) transpose x->fp16; [1408,1664) rel.
__global__ void k_prep_all(const float* __restrict__ Wq, const float* __restrict__ Wk,
                           const float* __restrict__ Wv, const float* __restrict__ bq,
                           const float* __restrict__ bk, const float* __restrict__ bv,
                           const float* __restrict__ x, const float* __restrict__ rel_h,
                           const float* __restrict__ rel_w, _Float16* __restrict__ Wf,
                           float* __restrict__ bias2, _Float16* __restrict__ xTf,
                           _Float16* __restrict__ rel2) {
    __shared__ float xs[64][65];
    int bid = blockIdx.x;
    if (bid < 384) {
        int t = bid * 256 + threadIdx.x;          // 98304 threads
        int m = t >> 6;
        int c8 = (t & 63) << 3;
        const float* src = (m < 512) ? (Wq + m * 512)
                         : (m < 1024 ? (Wk + (m - 512) * 512) : (Wv + (m - 1024) * 512));
        float4 v0 = *(const float4*)(src + c8);
        float4 v1 = *(const float4*)(src + c8 + 4);
        half8 o;
        o[0] = (_Float16)v0.x; o[1] = (_Float16)v0.y; o[2] = (_Float16)v0.z; o[3] = (_Float16)v0.w;
        o[4] = (_Float16)v1.x; o[5] = (_Float16)v1.y; o[6] = (_Float16)v1.z; o[7] = (_Float16)v1.w;
        *(half8*)(Wf + (size_t)m * 512 + c8) = o;
        if (t < 1536)
            bias2[t] = (t < 512) ? bq[t] : (t < 1024 ? bk[t - 512] : bv[t - 1024]);
    } else if (bid < 1408) {
        int i = bid - 384;
        int nt = (i & 15) << 6, ct = ((i >> 4) & 7) << 6, b = i >> 7;
        int t = threadIdx.x;
        const float* xb = x + ((size_t)b * 512 + ct) * 1024 + nt;
#pragma unroll
        for (int p = 0; p < 4; ++p) {
            int c = p * 16 + (t >> 4), n4 = (t & 15) * 4;
            float4 v = *(const float4*)(xb + (size_t)c * 1024 + n4);
            xs[c][n4] = v.x; xs[c][n4 + 1] = v.y; xs[c][n4 + 2] = v.z; xs[c][n4 + 3] = v.w;
        }
        __syncthreads();
        int nl = t >> 2, part = t & 3;
        _Float16* rowp = xTf + ((size_t)b * 1024 + nt + nl) * 512;
#pragma unroll
        for (int g = 0; g < 2; ++g) {
            half8 o;
#pragma unroll
            for (int j = 0; j < 8; ++j)
                o[j] = (_Float16)xs[part * 16 + g * 8 + j][nl];
            *(half8*)(rowp + ct + part * 16 + g * 8) = o;
        }
    } else {
        int tid = (bid - 1408) * 256 + threadIdx.x;   // 65536
        int h = tid >> 13;
        int rem = tid & 8191;
        int n = rem >> 3;
        int g = rem & 7;
        int hh = n & 31, ww = n >> 5;
        half8 o;
#pragma unroll
        for (int j = 0; j < 8; ++j) {
            int d = g * 8 + j;
            o[j] = (_Float16)(rel_h[(h * 64 + d) * 32 + hh] + rel_w[(h * 64 + d) * 32 + ww]);
        }
        *(half8*)(rel2 + ((size_t)h * 1024 + n) * 64 + g * 8) = o;
    }
}

// fp16 GEMM K=512, BK=64; glds16 + XOR-swizzled LDS (R0-proven).
__global__ __launch_bounds__(256, 3) void k_proj(const _Float16* __restrict__ Wf,
                                                 const _Float16* __restrict__ xTf,
                                                 const float* __restrict__ bias2,
                                                 _Float16* __restrict__ q2,
                                                 _Float16* __restrict__ k2,
                                                 _Float16* __restrict__ vb) {
    __shared__ __align__(16) _Float16 As[8192];   // [2 kh][128 rows][32 halfs], swizzled
    __shared__ __align__(16) _Float16 Bs[8192];
    int t = threadIdx.x;
    int lane = t & 63, w = t >> 6;
    int lm = lane & 15, lq = lane >> 4;
    int wr = (w >> 1) * 64, wc = (w & 1) * 64;
    int mb = blockIdx.y * 128, nb = blockIdx.x * 128, b = blockIdx.z;
    int rl = lane >> 2;                                   // row within 16-row group
    int csw = ((lane & 3) ^ ((lane >> 3) & 3)) * 8;       // swizzled col (halfs)
    const _Float16* Ag0 = Wf + (size_t)(mb + w * 32 + rl) * 512 + csw;
    const _Float16* Ag1 = Ag0 + 16 * 512;
    const _Float16* Bg0 = xTf + ((size_t)b * 1024 + nb + w * 32 + rl) * 512 + csw;
    const _Float16* Bg1 = Bg0 + 16 * 512;
    f32x4 acc[4][4];
#pragma unroll
    for (int i = 0; i < 4; ++i)
#pragma unroll
        for (int j = 0; j < 4; ++j) acc[i][j] = {0.f, 0.f, 0.f, 0.f};
    int fsw = (lq ^ ((lm >> 1) & 3)) * 8;                 // fragment-read swizzle
    for (int k0 = 0; k0 < 512; k0 += 64) {
#pragma unroll
        for (int kh = 0; kh < 2; ++kh) {
            int ko = k0 + kh * 32;
            glds16(Ag0 + ko, &As[kh * 4096 + (w * 32) * 32]);
            glds16(Ag1 + ko, &As[kh * 4096 + (w * 32 + 16) * 32]);
            glds16(Bg0 + ko, &Bs[kh * 4096 + (w * 32) * 32]);
            glds16(Bg1 + ko, &Bs[kh * 4096 + (w * 32 + 16) * 32]);
        }
        __syncthreads();
#pragma unroll
        for (int kh = 0; kh < 2; ++kh) {
            half8 af[4], bfr[4];
#pragma unroll
            for (int mt = 0; mt < 4; ++mt)
                af[mt] = *(half8*)&As[kh * 4096 + (wr + mt * 16 + lm) * 32 + fsw];
#pragma unroll
            for (int nt = 0; nt < 4; ++nt)
                bfr[nt] = *(half8*)&Bs[kh * 4096 + (wc + nt * 16 + lm) * 32 + fsw];
#pragma unroll
            for (int mt = 0; mt < 4; ++mt)
#pragma unroll
                for (int nt = 0; nt < 4; ++nt)
                    acc[mt][nt] = __builtin_amdgcn_mfma_f32_16x16x32_f16(af[mt], bfr[nt], acc[mt][nt], 0, 0, 0);
        }
        __syncthreads();
    }
    // Epilogue: section 0=q (x log2e), 1=k, 2=v; head-aligned since (mb+wr)%64==0.
    int sect = mb >> 9;
    int hloc = ((mb & 511) + wr) >> 6;
    size_t bh = (size_t)b * 8 + hloc;
    if (sect < 2) {
        float sc = (sect == 0) ? 1.44269504089f : 1.0f;
        _Float16* dst = (sect == 0 ? q2 : k2) + bh * 1024 * 64;
#pragma unroll
        for (int mt = 0; mt < 4; ++mt) {
            int d0 = mt * 16 + lq * 4;
            float bi0 = bias2[mb + wr + d0];
            float bi1 = bias2[mb + wr + d0 + 1];
            float bi2 = bias2[mb + wr + d0 + 2];
            float bi3 = bias2[mb + wr + d0 + 3];
#pragma unroll
            for (int nt = 0; nt < 4; ++nt) {
                int n = nb + wc + nt * 16 + lm;
                half4 o;
                o[0] = (_Float16)((acc[mt][nt][0] + bi0) * sc);
                o[1] = (_Float16)((acc[mt][nt][1] + bi1) * sc);
                o[2] = (_Float16)((acc[mt][nt][2] + bi2) * sc);
                o[3] = (_Float16)((acc[mt][nt][3] + bi3) * sc);
                *(half4*)(dst + (size_t)n * 64 + d0) = o;
            }
        }
    } else {
        _Float16* dst = vb + bh * 64 * 1024;
#pragma unroll
        for (int mt = 0; mt < 4; ++mt)
#pragma unroll
            for (int reg = 0; reg < 4; ++reg) {
                int d = mt * 16 + lq * 4 + reg;
                float bi = bias2[mb + wr + d];
#pragma unroll
                for (int nt = 0; nt < 4; ++nt) {
                    int n = nb + wc + nt * 16 + lm;
                    dst[(size_t)d * 1024 + n] = (_Float16)(acc[mt][nt][reg] + bi);
                }
            }
    }
}

// Flash attention, fp16, S^T orientation, Mtile=128. R10: P redistribution
// moved from LDS round-trip to VALU permlane swaps. Derivation: lane (lm,lq)
// holds P[m=w16+lm][n=ct*16+lq*4+reg]; PV B-frag needs P[m][n=ch*32+lq*8+j].
// cvt_pkrtz reg-pairs -> pk[ct][h]; permlane32_swap(pk[2c],pk[2c+1]) then
// permlane16_swap(same pair) lands every u32 at its target lane with uniform
// naming: frag[ch] = {pk[2ch][0],pk[2ch][1],pk[2ch+1][0],pk[2ch+1][1]}.
// p_s LDS buffer deleted (45056 -> 26624 B).
__global__ __launch_bounds__(256, 3) void k_attn(const _Float16* __restrict__ q2,
                                                 const _Float16* __restrict__ k2,
                                                 const _Float16* __restrict__ rel2,
                                                 const _Float16* __restrict__ vb,
                                                 float* __restrict__ out) {
    __shared__ __align__(16) char pool[26624];
    _Float16* kb_s = (_Float16*)pool;            // [64][136] = 17408 B
    _Float16* v_s  = (_Float16*)(pool + 17408);  // [64][72]  =  9216 B
    int t = threadIdx.x;
    int lane = t & 63, w = t >> 6;
    int lm = lane & 15, lq = lane >> 4;
    int lin = blockIdx.x;
    int mt0 = lin >> 6;          // 0..7 (128 q-rows each)
    int bh_ = lin & 63;
    int h = bh_ & 7, b = bh_ >> 3;
    size_t bh = (size_t)b * 8 + h;
    const _Float16* q2b = q2 + bh * 1024 * 64;
    const _Float16* k2b = k2 + bh * 1024 * 64;
    const _Float16* relb = rel2 + (size_t)h * 1024 * 64;
    const _Float16* vbb = vb + bh * 64 * 1024;
    float* outb = out + bh * 64 * 1024 + mt0 * 128;

    int r = t >> 2, part = t & 3;
    const _Float16* ksrc = ((part < 2) ? (k2b + part * 32) : (q2b + (part - 2) * 32));
    int vc = (t & 3) * 16;
    const _Float16* vsrcb = vbb + (size_t)r * 1024 + vc;
    _Float16* kdst = kb_s + r * 136 + part * 32;
    _Float16* vdst = v_s + r * 72 + vc;

    // prefetch tile 0 into named scalar registers
    uint4 kc0, kc1, kc2, kc3, vv0, vv1;
    {
        const uint4* s_ = (const uint4*)(ksrc + (size_t)r * 64);
        kc0 = s_[0]; kc1 = s_[1]; kc2 = s_[2]; kc3 = s_[3];
        const uint4* v_ = (const uint4*)vsrcb;
        vv0 = v_[0]; vv1 = v_[1];
    }

    // Phase 0 round A: stage A-rows [q | rel] for m = mt0*128 + 0..63
    {
        int n = mt0 * 128 + r;
        const _Float16* src = (part < 2) ? (q2b + (size_t)n * 64 + part * 32)
                                         : (relb + (size_t)n * 64 + (part - 2) * 32);
        ((uint4*)kdst)[0] = ((const uint4*)src)[0];
        ((uint4*)kdst)[1] = ((const uint4*)src)[1];
        ((uint4*)kdst)[2] = ((const uint4*)src)[2];
        ((uint4*)kdst)[3] = ((const uint4*)src)[3];
    }
    __syncthreads();
    half8 ah0[4], ah1[4];
#pragma unroll
    for (int kk = 0; kk < 4; ++kk)
        ah0[kk] = *(half8*)&kb_s[(w * 16 + lm) * 136 + kk * 32 + lq * 8];
    __syncthreads();
    // Phase 0 round B: rows m = mt0*128 + 64..127
    {
        int n = mt0 * 128 + 64 + r;
        const _Float16* src = (part < 2) ? (q2b + (size_t)n * 64 + part * 32)
                                         : (relb + (size_t)n * 64 + (part - 2) * 32);
        ((uint4*)kdst)[0] = ((const uint4*)src)[0];
        ((uint4*)kdst)[1] = ((const uint4*)src)[1];
        ((uint4*)kdst)[2] = ((const uint4*)src)[2];
        ((uint4*)kdst)[3] = ((const uint4*)src)[3];
    }
    __syncthreads();
#pragma unroll
    for (int kk = 0; kk < 4; ++kk)
        ah1[kk] = *(half8*)&kb_s[(w * 16 + lm) * 136 + kk * 32 + lq * 8];
    __syncthreads();   // ah1 reads complete before first K ds_write

    f32x4 acco0[4], acco1[4];
#pragma unroll
    for (int i = 0; i < 4; ++i) { acco0[i] = {0.f, 0.f, 0.f, 0.f}; acco1[i] = {0.f, 0.f, 0.f, 0.f}; }
    float mrun0 = -3e38f, lrun0 = 0.f, mrun1 = -3e38f, lrun1 = 0.f;

    for (int kt = 0; kt < 16; ++kt) {
        ((uint4*)kdst)[0] = kc0;
        ((uint4*)kdst)[1] = kc1;
        ((uint4*)kdst)[2] = kc2;
        ((uint4*)kdst)[3] = kc3;
        ((uint4*)vdst)[0] = vv0;
        ((uint4*)vdst)[1] = vv1;
        __syncthreads();
        int nn = ((kt + 1) & 15) * 64;
        const uint4* s_ = (const uint4*)(ksrc + (size_t)(nn + r) * 64);
        uint4 kn0 = s_[0], kn1 = s_[1], kn2 = s_[2], kn3 = s_[3];
        const uint4* v_ = (const uint4*)(vsrcb + nn);
        uint4 vn0 = v_[0], vn1 = v_[1];
        // S^T: s0/s1[ct][reg] -> n = ct*16 + lq*4 + reg, m = w*16 + lm (+64 for s1)
        f32x4 s0[4], s1[4];
#pragma unroll
        for (int ct = 0; ct < 4; ++ct) { s0[ct] = {0.f, 0.f, 0.f, 0.f}; s1[ct] = {0.f, 0.f, 0.f, 0.f}; }
#pragma unroll
        for (int ct = 0; ct < 4; ++ct) {
            half8 kf[4];
#pragma unroll
            for (int kk = 0; kk < 4; ++kk)
                kf[kk] = *(half8*)&kb_s[(ct * 16 + lm) * 136 + kk * 32 + lq * 8];
#pragma unroll
            for (int kk = 0; kk < 4; ++kk) {
                s0[ct] = __builtin_amdgcn_mfma_f32_16x16x32_f16(kf[kk], ah0[kk], s0[ct], 0, 0, 0);
                s1[ct] = __builtin_amdgcn_mfma_f32_16x16x32_f16(kf[kk], ah1[kk], s1[ct], 0, 0, 0);
            }
        }
        // softmax tile 0 (per-lane column m; exp2 domain) -> packed P in regs
        unsigned int pk0[4][2], pk1[4][2];
        {
            float mx = -3e38f;
#pragma unroll
            for (int ct = 0; ct < 4; ++ct)
#pragma unroll
                for (int reg = 0; reg < 4; ++reg) mx = fmaxf(mx, s0[ct][reg]);
            mx = fmaxf(mx, __shfl_xor(mx, 16));
            mx = fmaxf(mx, __shfl_xor(mx, 32));
            float mnew = fmaxf(mrun0, mx);
            float al_ = exp2f(mrun0 - mnew);
            float rs = 0.f;
#pragma unroll
            for (int ct = 0; ct < 4; ++ct) {
                float p0 = exp2f(s0[ct][0] - mnew);
                float p1 = exp2f(s0[ct][1] - mnew);
                float p2 = exp2f(s0[ct][2] - mnew);
                float p3 = exp2f(s0[ct][3] - mnew);
                rs += (p0 + p1) + (p2 + p3);
                pk0[ct][0] = __builtin_bit_cast(unsigned int, __builtin_amdgcn_cvt_pkrtz(p0, p1));
                pk0[ct][1] = __builtin_bit_cast(unsigned int, __builtin_amdgcn_cvt_pkrtz(p2, p3));
            }
            rs += __shfl_xor(rs, 16);
            rs += __shfl_xor(rs, 32);
            lrun0 = lrun0 * al_ + rs;
            mrun0 = mnew;
#pragma unroll
            for (int dt = 0; dt < 4; ++dt) {
                acco0[dt][0] *= al_; acco0[dt][1] *= al_;
                acco0[dt][2] *= al_; acco0[dt][3] *= al_;
            }
        }
        // softmax tile 1
        {
            float mx = -3e38f;
#pragma unroll
            for (int ct = 0; ct < 4; ++ct)
#pragma unroll
                for (int reg = 0; reg < 4; ++reg) mx = fmaxf(mx, s1[ct][reg]);
            mx = fmaxf(mx, __shfl_xor(mx, 16));
            mx = fmaxf(mx, __shfl_xor(mx, 32));
            float mnew = fmaxf(mrun1, mx);
            float al_ = exp2f(mrun1 - mnew);
            float rs = 0.f;
#pragma unroll
            for (int ct = 0; ct < 4; ++ct) {
                float p0 = exp2f(s1[ct][0] - mnew);
                float p1 = exp2f(s1[ct][1] - mnew);
                float p2 = exp2f(s1[ct][2] - mnew);
                float p3 = exp2f(s1[ct][3] - mnew);
                rs += (p0 + p1) + (p2 + p3);
                pk1[ct][0] = __builtin_bit_cast(unsigned int, __builtin_amdgcn_cvt_pkrtz(p0, p1));
                pk1[ct][1] = __builtin_bit_cast(unsigned int, __builtin_amdgcn_cvt_pkrtz(p2, p3));
            }
            rs += __shfl_xor(rs, 16);
            rs += __shfl_xor(rs, 32);
            lrun1 = lrun1 * al_ + rs;
            mrun1 = mnew;
#pragma unroll
            for (int dt = 0; dt < 4; ++dt) {
                acco1[dt][0] *= al_; acco1[dt][1] *= al_;
                acco1[dt][2] *= al_; acco1[dt][3] *= al_;
            }
        }
        // P redistribution: 2-stage butterfly in VALU (no LDS)
        swap32(pk0[0][0], pk0[1][0]); swap32(pk0[0][1], pk0[1][1]);
        swap32(pk0[2][0], pk0[3][0]); swap32(pk0[2][1], pk0[3][1]);
        swap16(pk0[0][0], pk0[1][0]); swap16(pk0[0][1], pk0[1][1]);
        swap16(pk0[2][0], pk0[3][0]); swap16(pk0[2][1], pk0[3][1]);
        swap32(pk1[0][0], pk1[1][0]); swap32(pk1[0][1], pk1[1][1]);
        swap32(pk1[2][0], pk1[3][0]); swap32(pk1[2][1], pk1[3][1]);
        swap16(pk1[0][0], pk1[1][0]); swap16(pk1[0][1], pk1[1][1]);
        swap16(pk1[2][0], pk1[3][0]); swap16(pk1[2][1], pk1[3][1]);
        half8 p0f[2], p1f[2];
        {
            unsigned int* u;
            u = (unsigned int*)&p0f[0]; u[0] = pk0[0][0]; u[1] = pk0[0][1]; u[2] = pk0[1][0]; u[3] = pk0[1][1];
            u = (unsigned int*)&p0f[1]; u[0] = pk0[2][0]; u[1] = pk0[2][1]; u[2] = pk0[3][0]; u[3] = pk0[3][1];
            u = (unsigned int*)&p1f[0]; u[0] = pk1[0][0]; u[1] = pk1[0][1]; u[2] = pk1[1][0]; u[3] = pk1[1][1];
            u = (unsigned int*)&p1f[1]; u[0] = pk1[2][0]; u[1] = pk1[2][1]; u[2] = pk1[3][0]; u[3] = pk1[3][1];
        }
        // PV for both tiles; v fragments shared
#pragma unroll
        for (int dt = 0; dt < 4; ++dt) {
            half8 vf0 = *(half8*)&v_s[(dt * 16 + lm) * 72 + lq * 8];
            half8 vf1 = *(half8*)&v_s[(dt * 16 + lm) * 72 + 32 + lq * 8];
            acco0[dt] = __builtin_amdgcn_mfma_f32_16x16x32_f16(vf0, p0f[0], acco0[dt], 0, 0, 0);
            acco0[dt] = __builtin_amdgcn_mfma_f32_16x16x32_f16(vf1, p0f[1], acco0[dt], 0, 0, 0);
            acco1[dt] = __builtin_amdgcn_mfma_f32_16x16x32_f16(vf0, p1f[0], acco1[dt], 0, 0, 0);
            acco1[dt] = __builtin_amdgcn_mfma_f32_16x16x32_f16(vf1, p1f[1], acco1[dt], 0, 0, 0);
        }
        __syncthreads();   // all reads of kb_s/v_s done before next ds_write
        kc0 = kn0; kc1 = kn1; kc2 = kn2; kc3 = kn3;
        vv0 = vn0; vv1 = vn1;
    }
    float li0 = 1.f / lrun0, li1 = 1.f / lrun1;
#pragma unroll
    for (int dt = 0; dt < 4; ++dt)
#pragma unroll
        for (int reg = 0; reg < 4; ++reg) {
            int d = dt * 16 + lq * 4 + reg;
            outb[(size_t)d * 1024 + w * 16 + lm] = acco0[dt][reg] * li0;
            outb[(size_t)d * 1024 + 64 + w * 16 + lm] = acco1[dt][reg] * li1;
        }
}

extern "C" void kernel_launch(void* const* d_in, const int* in_sizes, int n_in,
                              void* d_out, int out_size, void* d_ws, size_t ws_size,
                              hipStream_t stream) {
    const float* x     = (const float*)d_in[0];
    const float* Wq    = (const float*)d_in[1];
    const float* bq    = (const float*)d_in[2];
    const float* Wk    = (const float*)d_in[3];
    const float* bk    = (const float*)d_in[4];
    const float* Wv    = (const float*)d_in[5];
    const float* bv    = (const float*)d_in[6];
    const float* rel_h = (const float*)d_in[7];
    const float* rel_w = (const float*)d_in[8];
    char* ws = (char*)d_ws;
    _Float16* Wf   = (_Float16*)(ws);               //  1,572,864 B
    float* bias2   = (float*)(ws + 1572864);        //      6,144 B -> 1,579,008
    _Float16* xTf  = (_Float16*)(ws + 1579008);     //  8,388,608 B -> 9,967,616
    _Float16* q2   = (_Float16*)(ws + 9967616);     //  8,388,608 B -> 18,356,224
    _Float16* k2   = (_Float16*)(ws + 18356224);    //  8,388,608 B -> 26,744,832
    _Float16* vb   = (_Float16*)(ws + 26744832);    //  8,388,608 B -> 35,133,440
    _Float16* rel2 = (_Float16*)(ws + 35133440);    //  1,048,576 B -> 36,182,016
    float* out = (float*)d_out;

    hipLaunchKernelGGL(k_prep_all, dim3(1664),     dim3(256), 0, stream,
                       Wq, Wk, Wv, bq, bk, bv, x, rel_h, rel_w, Wf, bias2, xTf, rel2);
    hipLaunchKernelGGL(k_proj,     dim3(8, 12, 8), dim3(256), 0, stream, Wf, xTf, bias2, q2, k2, vb);
    hipLaunchKernelGGL(k_attn,     dim3(512),      dim3(256), 0, stream, q2, k2, rel2, vb, out);
}

// Round 11
// 150.975 us; speedup vs baseline: 1.1182x; 1.0382x over previous
//
#include <hip/hip_runtime.h>

typedef _Float16 half8 __attribute__((ext_vector_type(8)));
typedef _Float16 half4 __attribute__((ext_vector_type(4)));
typedef __fp16 fp16x2 __attribute__((ext_vector_type(2)));
typedef float f32x4 __attribute__((ext_vector_type(4)));

__device__ __forceinline__ void glds16(const void* g, void* l) {
    __builtin_amdgcn_global_load_lds(
        (const __attribute__((address_space(1))) unsigned int*)g,
        (__attribute__((address_space(3))) unsigned int*)l, 16, 0, 0);
}

// gfx950 VALU cross-lane swaps (both operands modified).
__device__ __forceinline__ void swap32(unsigned int& a, unsigned int& b) {
    asm volatile("v_permlane32_swap_b32 %0, %1" : "+v"(a), "+v"(b));
}
__device__ __forceinline__ void swap16(unsigned int& a, unsigned int& b) {
    asm volatile("v_permlane16_swap_b32 %0, %1" : "+v"(a), "+v"(b));
}

// ---------------------------------------------------------------------------
// Sizes: B=8, C=512, H=8, D=64, N=1024. Projection: M=1536 (q|k|v), K=512.
// R11: prep_xt DELETED. proj stages B directly from raw x[b][c][n] into the
// R0-proven Bs layout (pitch 32, XOR map LDS[row][g]=global[row][g^((row>>1)&3)])
// — read side byte-identical to R0. Prep = W-pack + bias + rel only (640 blk).
// ---------------------------------------------------------------------------

// [0,384): W pack -> fp16 + bias gather; [384,640): rel2 = rel_h+rel_w fp16.
__global__ void k_prep_wrel(const float* __restrict__ Wq, const float* __restrict__ Wk,
                            const float* __restrict__ Wv, const float* __restrict__ bq,
                            const float* __restrict__ bk, const float* __restrict__ bv,
                            const float* __restrict__ rel_h, const float* __restrict__ rel_w,
                            _Float16* __restrict__ Wf, float* __restrict__ bias2,
                            _Float16* __restrict__ rel2) {
    int bid = blockIdx.x;
    if (bid < 384) {
        int t = bid * 256 + threadIdx.x;          // 98304 threads
        int m = t >> 6;
        int c8 = (t & 63) << 3;
        const float* src = (m < 512) ? (Wq + m * 512)
                         : (m < 1024 ? (Wk + (m - 512) * 512) : (Wv + (m - 1024) * 512));
        float4 v0 = *(const float4*)(src + c8);
        float4 v1 = *(const float4*)(src + c8 + 4);
        half8 o;
        o[0] = (_Float16)v0.x; o[1] = (_Float16)v0.y; o[2] = (_Float16)v0.z; o[3] = (_Float16)v0.w;
        o[4] = (_Float16)v1.x; o[5] = (_Float16)v1.y; o[6] = (_Float16)v1.z; o[7] = (_Float16)v1.w;
        *(half8*)(Wf + (size_t)m * 512 + c8) = o;
        if (t < 1536)
            bias2[t] = (t < 512) ? bq[t] : (t < 1024 ? bk[t - 512] : bv[t - 1024]);
    } else {
        int tid = (bid - 384) * 256 + threadIdx.x;   // 65536
        int h = tid >> 13;
        int rem = tid & 8191;
        int n = rem >> 3;
        int g = rem & 7;
        int hh = n & 31, ww = n >> 5;
        half8 o;
#pragma unroll
        for (int j = 0; j < 8; ++j) {
            int d = g * 8 + j;
            o[j] = (_Float16)(rel_h[(h * 64 + d) * 32 + hh] + rel_w[(h * 64 + d) * 32 + ww]);
        }
        *(half8*)(rel2 + ((size_t)h * 1024 + n) * 64 + g * 8) = o;
    }
}

// fp16 GEMM K=512, BK=64. A: glds16 from Wf + XOR swizzle (R0-proven).
// B: raw x -> in-register transpose (LITERAL j indices) -> ds_write into the
// SAME Bs layout R0 used: Bs[kh*4096 + r*32 + (g2^((r>>1)&3))*8]. Fragment
// reads (fsw) byte-identical to R0 -> proven 2-way-free. Write pattern: bank
// base 16(j&1)+4*g_dst, g_dst spans 4 values/wave -> 16 banks, ~2x (ok).
__global__ __launch_bounds__(256, 3) void k_projb(const _Float16* __restrict__ Wf,
                                                  const float* __restrict__ x,
                                                  const float* __restrict__ bias2,
                                                  _Float16* __restrict__ q2,
                                                  _Float16* __restrict__ k2,
                                                  _Float16* __restrict__ vb) {
    __shared__ __align__(16) _Float16 As[8192];   // [2 kh][128 rows][32 halfs], swizzled
    __shared__ __align__(16) _Float16 Bs[8192];
    int t = threadIdx.x;
    int lane = t & 63, w = t >> 6;
    int lm = lane & 15, lq = lane >> 4;
    int wr = (w >> 1) * 64, wc = (w & 1) * 64;
    int mb = blockIdx.y * 128, nbase = blockIdx.x * 128, b = blockIdx.z;
    int rl = lane >> 2;                                   // row within 16-row group
    int csw = ((lane & 3) ^ ((lane >> 3) & 3)) * 8;       // swizzled col (halfs)
    const _Float16* Ag0 = Wf + (size_t)(mb + w * 32 + rl) * 512 + csw;
    const _Float16* Ag1 = Ag0 + 16 * 512;
    // B staging map: nq -> rows 4nq..4nq+3 (n-local), ch -> c-octet (8 halfs)
    int nq = t & 31;
    int ch = t >> 5;                     // 0..7
    int bkh = ch >> 2;                   // K-half
    int g2 = ch & 3;                     // global group within K-half
    const float* xb = x + (size_t)b * 512 * 1024 + nbase + nq * 4;
    f32x4 acc[4][4];
#pragma unroll
    for (int i = 0; i < 4; ++i)
#pragma unroll
        for (int j = 0; j < 4; ++j) acc[i][j] = {0.f, 0.f, 0.f, 0.f};
    int fsw = (lq ^ ((lm >> 1) & 3)) * 8;                 // fragment-read swizzle
    for (int k0 = 0; k0 < 512; k0 += 64) {
        // ---- A: glds16 (unchanged from R0) ----
#pragma unroll
        for (int kh = 0; kh < 2; ++kh) {
            int ko = k0 + kh * 32;
            glds16(Ag0 + ko, &As[kh * 4096 + (w * 32) * 32]);
            glds16(Ag1 + ko, &As[kh * 4096 + (w * 32 + 16) * 32]);
        }
        // ---- B: raw x (coalesced along n) -> reg transpose -> swizzled Bs ----
        {
            const float* xp = xb + (size_t)(k0 + ch * 8) * 1024;
            float4 xf0 = *(const float4*)(xp);
            float4 xf1 = *(const float4*)(xp + 1024);
            float4 xf2 = *(const float4*)(xp + 2048);
            float4 xf3 = *(const float4*)(xp + 3072);
            float4 xf4 = *(const float4*)(xp + 4096);
            float4 xf5 = *(const float4*)(xp + 5120);
            float4 xf6 = *(const float4*)(xp + 6144);
            float4 xf7 = *(const float4*)(xp + 7168);
            _Float16* bsh = &Bs[bkh * 4096];
#define STAGE_ROW(j, c0, c1, c2, c3, c4, c5, c6, c7)                     \
            {                                                            \
                int r = nq * 4 + j;                                      \
                int gd = g2 ^ ((r >> 1) & 3);                            \
                half8 h;                                                 \
                h[0] = (_Float16)c0; h[1] = (_Float16)c1;                \
                h[2] = (_Float16)c2; h[3] = (_Float16)c3;                \
                h[4] = (_Float16)c4; h[5] = (_Float16)c5;                \
                h[6] = (_Float16)c6; h[7] = (_Float16)c7;                \
                *(half8*)&bsh[r * 32 + gd * 8] = h;                      \
            }
            STAGE_ROW(0, xf0.x, xf1.x, xf2.x, xf3.x, xf4.x, xf5.x, xf6.x, xf7.x)
            STAGE_ROW(1, xf0.y, xf1.y, xf2.y, xf3.y, xf4.y, xf5.y, xf6.y, xf7.y)
            STAGE_ROW(2, xf0.z, xf1.z, xf2.z, xf3.z, xf4.z, xf5.z, xf6.z, xf7.z)
            STAGE_ROW(3, xf0.w, xf1.w, xf2.w, xf3.w, xf4.w, xf5.w, xf6.w, xf7.w)
#undef STAGE_ROW
        }
        __syncthreads();
#pragma unroll
        for (int kh = 0; kh < 2; ++kh) {
            half8 af[4], bfr[4];
#pragma unroll
            for (int mt = 0; mt < 4; ++mt)
                af[mt] = *(half8*)&As[kh * 4096 + (wr + mt * 16 + lm) * 32 + fsw];
#pragma unroll
            for (int nt = 0; nt < 4; ++nt)
                bfr[nt] = *(half8*)&Bs[kh * 4096 + (wc + nt * 16 + lm) * 32 + fsw];
#pragma unroll
            for (int mt = 0; mt < 4; ++mt)
#pragma unroll
                for (int nt = 0; nt < 4; ++nt)
                    acc[mt][nt] = __builtin_amdgcn_mfma_f32_16x16x32_f16(af[mt], bfr[nt], acc[mt][nt], 0, 0, 0);
        }
        __syncthreads();
    }
    // Epilogue: section 0=q (x log2e), 1=k, 2=v; head-aligned since (mb+wr)%64==0.
    int sect = mb >> 9;
    int hloc = ((mb & 511) + wr) >> 6;
    size_t bh = (size_t)b * 8 + hloc;
    if (sect < 2) {
        float sc = (sect == 0) ? 1.44269504089f : 1.0f;
        _Float16* dst = (sect == 0 ? q2 : k2) + bh * 1024 * 64;
#pragma unroll
        for (int mt = 0; mt < 4; ++mt) {
            int d0 = mt * 16 + lq * 4;
            float bi0 = bias2[mb + wr + d0];
            float bi1 = bias2[mb + wr + d0 + 1];
            float bi2 = bias2[mb + wr + d0 + 2];
            float bi3 = bias2[mb + wr + d0 + 3];
#pragma unroll
            for (int nt = 0; nt < 4; ++nt) {
                int n = nbase + wc + nt * 16 + lm;
                half4 o;
                o[0] = (_Float16)((acc[mt][nt][0] + bi0) * sc);
                o[1] = (_Float16)((acc[mt][nt][1] + bi1) * sc);
                o[2] = (_Float16)((acc[mt][nt][2] + bi2) * sc);
                o[3] = (_Float16)((acc[mt][nt][3] + bi3) * sc);
                *(half4*)(dst + (size_t)n * 64 + d0) = o;
            }
        }
    } else {
        _Float16* dst = vb + bh * 64 * 1024;
#pragma unroll
        for (int mt = 0; mt < 4; ++mt)
#pragma unroll
            for (int reg = 0; reg < 4; ++reg) {
                int d = mt * 16 + lq * 4 + reg;
                float bi = bias2[mb + wr + d];
#pragma unroll
                for (int nt = 0; nt < 4; ++nt) {
                    int n = nbase + wc + nt * 16 + lm;
                    dst[(size_t)d * 1024 + n] = (_Float16)(acc[mt][nt][reg] + bi);
                }
            }
    }
}

// Flash attention, fp16, S^T orientation, Mtile=128. R10 version (verified):
// P redistribution via VALU permlane swaps, p_s LDS deleted (26624 B pool).
__global__ __launch_bounds__(256, 3) void k_attn(const _Float16* __restrict__ q2,
                                                 const _Float16* __restrict__ k2,
                                                 const _Float16* __restrict__ rel2,
                                                 const _Float16* __restrict__ vb,
                                                 float* __restrict__ out) {
    __shared__ __align__(16) char pool[26624];
    _Float16* kb_s = (_Float16*)pool;            // [64][136] = 17408 B
    _Float16* v_s  = (_Float16*)(pool + 17408);  // [64][72]  =  9216 B
    int t = threadIdx.x;
    int lane = t & 63, w = t >> 6;
    int lm = lane & 15, lq = lane >> 4;
    int lin = blockIdx.x;
    int mt0 = lin >> 6;          // 0..7 (128 q-rows each)
    int bh_ = lin & 63;
    int h = bh_ & 7, b = bh_ >> 3;
    size_t bh = (size_t)b * 8 + h;
    const _Float16* q2b = q2 + bh * 1024 * 64;
    const _Float16* k2b = k2 + bh * 1024 * 64;
    const _Float16* relb = rel2 + (size_t)h * 1024 * 64;
    const _Float16* vbb = vb + bh * 64 * 1024;
    float* outb = out + bh * 64 * 1024 + mt0 * 128;

    int r = t >> 2, part = t & 3;
    const _Float16* ksrc = ((part < 2) ? (k2b + part * 32) : (q2b + (part - 2) * 32));
    int vc = (t & 3) * 16;
    const _Float16* vsrcb = vbb + (size_t)r * 1024 + vc;
    _Float16* kdst = kb_s + r * 136 + part * 32;
    _Float16* vdst = v_s + r * 72 + vc;

    // prefetch tile 0 into named scalar registers
    uint4 kc0, kc1, kc2, kc3, vv0, vv1;
    {
        const uint4* s_ = (const uint4*)(ksrc + (size_t)r * 64);
        kc0 = s_[0]; kc1 = s_[1]; kc2 = s_[2]; kc3 = s_[3];
        const uint4* v_ = (const uint4*)vsrcb;
        vv0 = v_[0]; vv1 = v_[1];
    }

    // Phase 0 round A: stage A-rows [q | rel] for m = mt0*128 + 0..63
    {
        int n = mt0 * 128 + r;
        const _Float16* src = (part < 2) ? (q2b + (size_t)n * 64 + part * 32)
                                         : (relb + (size_t)n * 64 + (part - 2) * 32);
        ((uint4*)kdst)[0] = ((const uint4*)src)[0];
        ((uint4*)kdst)[1] = ((const uint4*)src)[1];
        ((uint4*)kdst)[2] = ((const uint4*)src)[2];
        ((uint4*)kdst)[3] = ((const uint4*)src)[3];
    }
    __syncthreads();
    half8 ah0[4], ah1[4];
#pragma unroll
    for (int kk = 0; kk < 4; ++kk)
        ah0[kk] = *(half8*)&kb_s[(w * 16 + lm) * 136 + kk * 32 + lq * 8];
    __syncthreads();
    // Phase 0 round B: rows m = mt0*128 + 64..127
    {
        int n = mt0 * 128 + 64 + r;
        const _Float16* src = (part < 2) ? (q2b + (size_t)n * 64 + part * 32)
                                         : (relb + (size_t)n * 64 + (part - 2) * 32);
        ((uint4*)kdst)[0] = ((const uint4*)src)[0];
        ((uint4*)kdst)[1] = ((const uint4*)src)[1];
        ((uint4*)kdst)[2] = ((const uint4*)src)[2];
        ((uint4*)kdst)[3] = ((const uint4*)src)[3];
    }
    __syncthreads();
#pragma unroll
    for (int kk = 0; kk < 4; ++kk)
        ah1[kk] = *(half8*)&kb_s[(w * 16 + lm) * 136 + kk * 32 + lq * 8];
    __syncthreads();   // ah1 reads complete before first K ds_write

    f32x4 acco0[4], acco1[4];
#pragma unroll
    for (int i = 0; i < 4; ++i) { acco0[i] = {0.f, 0.f, 0.f, 0.f}; acco1[i] = {0.f, 0.f, 0.f, 0.f}; }
    float mrun0 = -3e38f, lrun0 = 0.f, mrun1 = -3e38f, lrun1 = 0.f;

    for (int kt = 0; kt < 16; ++kt) {
        ((uint4*)kdst)[0] = kc0;
        ((uint4*)kdst)[1] = kc1;
        ((uint4*)kdst)[2] = kc2;
        ((uint4*)kdst)[3] = kc3;
        ((uint4*)vdst)[0] = vv0;
        ((uint4*)vdst)[1] = vv1;
        __syncthreads();
        int nn = ((kt + 1) & 15) * 64;
        const uint4* s_ = (const uint4*)(ksrc + (size_t)(nn + r) * 64);
        uint4 kn0 = s_[0], kn1 = s_[1], kn2 = s_[2], kn3 = s_[3];
        const uint4* v_ = (const uint4*)(vsrcb + nn);
        uint4 vn0 = v_[0], vn1 = v_[1];
        // S^T: s0/s1[ct][reg] -> n = ct*16 + lq*4 + reg, m = w*16 + lm (+64 for s1)
        f32x4 s0[4], s1[4];
#pragma unroll
        for (int ct = 0; ct < 4; ++ct) { s0[ct] = {0.f, 0.f, 0.f, 0.f}; s1[ct] = {0.f, 0.f, 0.f, 0.f}; }
#pragma unroll
        for (int ct = 0; ct < 4; ++ct) {
            half8 kf[4];
#pragma unroll
            for (int kk = 0; kk < 4; ++kk)
                kf[kk] = *(half8*)&kb_s[(ct * 16 + lm) * 136 + kk * 32 + lq * 8];
#pragma unroll
            for (int kk = 0; kk < 4; ++kk) {
                s0[ct] = __builtin_amdgcn_mfma_f32_16x16x32_f16(kf[kk], ah0[kk], s0[ct], 0, 0, 0);
                s1[ct] = __builtin_amdgcn_mfma_f32_16x16x32_f16(kf[kk], ah1[kk], s1[ct], 0, 0, 0);
            }
        }
        // softmax tile 0 (per-lane column m; exp2 domain) -> packed P in regs
        unsigned int pk0[4][2], pk1[4][2];
        {
            float mx = -3e38f;
#pragma unroll
            for (int ct = 0; ct < 4; ++ct)
#pragma unroll
                for (int reg = 0; reg < 4; ++reg) mx = fmaxf(mx, s0[ct][reg]);
            mx = fmaxf(mx, __shfl_xor(mx, 16));
            mx = fmaxf(mx, __shfl_xor(mx, 32));
            float mnew = fmaxf(mrun0, mx);
            float al_ = exp2f(mrun0 - mnew);
            float rs = 0.f;
#pragma unroll
            for (int ct = 0; ct < 4; ++ct) {
                float p0 = exp2f(s0[ct][0] - mnew);
                float p1 = exp2f(s0[ct][1] - mnew);
                float p2 = exp2f(s0[ct][2] - mnew);
                float p3 = exp2f(s0[ct][3] - mnew);
                rs += (p0 + p1) + (p2 + p3);
                pk0[ct][0] = __builtin_bit_cast(unsigned int, __builtin_amdgcn_cvt_pkrtz(p0, p1));
                pk0[ct][1] = __builtin_bit_cast(unsigned int, __builtin_amdgcn_cvt_pkrtz(p2, p3));
            }
            rs += __shfl_xor(rs, 16);
            rs += __shfl_xor(rs, 32);
            lrun0 = lrun0 * al_ + rs;
            mrun0 = mnew;
#pragma unroll
            for (int dt = 0; dt < 4; ++dt) {
                acco0[dt][0] *= al_; acco0[dt][1] *= al_;
                acco0[dt][2] *= al_; acco0[dt][3] *= al_;
            }
        }
        // softmax tile 1
        {
            float mx = -3e38f;
#pragma unroll
            for (int ct = 0; ct < 4; ++ct)
#pragma unroll
                for (int reg = 0; reg < 4; ++reg) mx = fmaxf(mx, s1[ct][reg]);
            mx = fmaxf(mx, __shfl_xor(mx, 16));
            mx = fmaxf(mx, __shfl_xor(mx, 32));
            float mnew = fmaxf(mrun1, mx);
            float al_ = exp2f(mrun1 - mnew);
            float rs = 0.f;
#pragma unroll
            for (int ct = 0; ct < 4; ++ct) {
                float p0 = exp2f(s1[ct][0] - mnew);
                float p1 = exp2f(s1[ct][1] - mnew);
                float p2 = exp2f(s1[ct][2] - mnew);
                float p3 = exp2f(s1[ct][3] - mnew);
                rs += (p0 + p1) + (p2 + p3);
                pk1[ct][0] = __builtin_bit_cast(unsigned int, __builtin_amdgcn_cvt_pkrtz(p0, p1));
                pk1[ct][1] = __builtin_bit_cast(unsigned int, __builtin_amdgcn_cvt_pkrtz(p2, p3));
            }
            rs += __shfl_xor(rs, 16);
            rs += __shfl_xor(rs, 32);
            lrun1 = lrun1 * al_ + rs;
            mrun1 = mnew;
#pragma unroll
            for (int dt = 0; dt < 4; ++dt) {
                acco1[dt][0] *= al_; acco1[dt][1] *= al_;
                acco1[dt][2] *= al_; acco1[dt][3] *= al_;
            }
        }
        // P redistribution: 2-stage butterfly in VALU (no LDS)
        swap32(pk0[0][0], pk0[1][0]); swap32(pk0[0][1], pk0[1][1]);
        swap32(pk0[2][0], pk0[3][0]); swap32(pk0[2][1], pk0[3][1]);
        swap16(pk0[0][0], pk0[1][0]); swap16(pk0[0][1], pk0[1][1]);
        swap16(pk0[2][0], pk0[3][0]); swap16(pk0[2][1], pk0[3][1]);
        swap32(pk1[0][0], pk1[1][0]); swap32(pk1[0][1], pk1[1][1]);
        swap32(pk1[2][0], pk1[3][0]); swap32(pk1[2][1], pk1[3][1]);
        swap16(pk1[0][0], pk1[1][0]); swap16(pk1[0][1], pk1[1][1]);
        swap16(pk1[2][0], pk1[3][0]); swap16(pk1[2][1], pk1[3][1]);
        half8 p0f[2], p1f[2];
        {
            unsigned int* u;
            u = (unsigned int*)&p0f[0]; u[0] = pk0[0][0]; u[1] = pk0[0][1]; u[2] = pk0[1][0]; u[3] = pk0[1][1];
            u = (unsigned int*)&p0f[1]; u[0] = pk0[2][0]; u[1] = pk0[2][1]; u[2] = pk0[3][0]; u[3] = pk0[3][1];
            u = (unsigned int*)&p1f[0]; u[0] = pk1[0][0]; u[1] = pk1[0][1]; u[2] = pk1[1][0]; u[3] = pk1[1][1];
            u = (unsigned int*)&p1f[1]; u[0] = pk1[2][0]; u[1] = pk1[2][1]; u[2] = pk1[3][0]; u[3] = pk1[3][1];
        }
        // PV for both tiles; v fragments shared
#pragma unroll
        for (int dt = 0; dt < 4; ++dt) {
            half8 vf0 = *(half8*)&v_s[(dt * 16 + lm) * 72 + lq * 8];
            half8 vf1 = *(half8*)&v_s[(dt * 16 + lm) * 72 + 32 + lq * 8];
            acco0[dt] = __builtin_amdgcn_mfma_f32_16x16x32_f16(vf0, p0f[0], acco0[dt], 0, 0, 0);
            acco0[dt] = __builtin_amdgcn_mfma_f32_16x16x32_f16(vf1, p0f[1], acco0[dt], 0, 0, 0);
            acco1[dt] = __builtin_amdgcn_mfma_f32_16x16x32_f16(vf0, p1f[0], acco1[dt], 0, 0, 0);
            acco1[dt] = __builtin_amdgcn_mfma_f32_16x16x32_f16(vf1, p1f[1], acco1[dt], 0, 0, 0);
        }
        __syncthreads();   // all reads of kb_s/v_s done before next ds_write
        kc0 = kn0; kc1 = kn1; kc2 = kn2; kc3 = kn3;
        vv0 = vn0; vv1 = vn1;
    }
    float li0 = 1.f / lrun0, li1 = 1.f / lrun1;
#pragma unroll
    for (int dt = 0; dt < 4; ++dt)
#pragma unroll
        for (int reg = 0; reg < 4; ++reg) {
            int d = dt * 16 + lq * 4 + reg;
            outb[(size_t)d * 1024 + w * 16 + lm] = acco0[dt][reg] * li0;
            outb[(size_t)d * 1024 + 64 + w * 16 + lm] = acco1[dt][reg] * li1;
        }
}

extern "C" void kernel_launch(void* const* d_in, const int* in_sizes, int n_in,
                              void* d_out, int out_size, void* d_ws, size_t ws_size,
                              hipStream_t stream) {
    const float* x     = (const float*)d_in[0];
    const float* Wq    = (const float*)d_in[1];
    const float* bq    = (const float*)d_in[2];
    const float* Wk    = (const float*)d_in[3];
    const float* bk    = (const float*)d_in[4];
    const float* Wv    = (const float*)d_in[5];
    const float* bv    = (const float*)d_in[6];
    const float* rel_h = (const float*)d_in[7];
    const float* rel_w = (const float*)d_in[8];
    char* ws = (char*)d_ws;
    _Float16* Wf   = (_Float16*)(ws);               //  1,572,864 B
    float* bias2   = (float*)(ws + 1572864);        //      6,144 B -> 1,579,008
    _Float16* q2   = (_Float16*)(ws + 1579008);     //  8,388,608 B -> 9,967,616
    _Float16* k2   = (_Float16*)(ws + 9967616);     //  8,388,608 B -> 18,356,224
    _Float16* vb   = (_Float16*)(ws + 18356224);    //  8,388,608 B -> 26,744,832
    _Float16* rel2 = (_Float16*)(ws + 26744832);    //  1,048,576 B -> 27,793,408
    float* out = (float*)d_out;

    hipLaunchKernelGGL(k_prep_wrel, dim3(640),      dim3(256), 0, stream,
                       Wq, Wk, Wv, bq, bk, bv, rel_h, rel_w, Wf, bias2, rel2);
    hipLaunchKernelGGL(k_projb,     dim3(8, 12, 8), dim3(256), 0, stream, Wf, x, bias2, q2, k2, vb);
    hipLaunchKernelGGL(k_attn,      dim3(512),      dim3(256), 0, stream, q2, k2, rel2, vb, out);
}